// Round 23
// baseline (46.612 us; speedup 1.0000x reference)
//
#include <hip/hip_runtime.h>
#include <hip/hip_bf16.h>

#define NR  8192      // rows per view
#define M   16384     // 2*NR concatenated
#define SUBB 16384    // 256 cols * 64 B (one fp4 Y sub-tile)

constexpr float INV_T   = 2.5f;                  // 1/0.4
constexpr float SCALE_S = 1.89914134f;           // sqrt(2.5*log2(e)); s^2=2.5*log2e
constexpr float E_REFL  = 12.182493960703473f;   // exp(2.5)
constexpr unsigned SCALE_Q = 0x7C7C7C7Cu;        // e8m0 = 2^-3 in all bytes
constexpr float FOLD = 8.0f * SCALE_S;           // x8 fold, 2^-3 scale each side

typedef int   i32x4 __attribute__((ext_vector_type(4)));
typedef int   i32x8 __attribute__((ext_vector_type(8)));
typedef float f32x4 __attribute__((ext_vector_type(4)));

typedef const __attribute__((address_space(1))) unsigned int* gas_u32;
typedef __attribute__((address_space(3))) unsigned int*       las_u32;

__device__ __forceinline__ float fexp2(float x) {
#if __has_builtin(__builtin_amdgcn_exp2f)
    return __builtin_amdgcn_exp2f(x);
#else
    return exp2f(x);
#endif
}

// fp4 e2m1 encode (round-to-nearest): values {0,.5,1,1.5,2,3,4,6}, bit3=sign
__device__ __forceinline__ unsigned f4enc(float v) {
    unsigned s = v < 0.0f ? 8u : 0u;
    float m = fabsf(v);
    unsigned c = (m < 0.25f) ? 0u : (m < 0.75f) ? 1u : (m < 1.25f) ? 2u :
                 (m < 1.75f) ? 3u : (m < 2.5f)  ? 4u : (m < 3.5f)  ? 5u :
                 (m < 5.0f)  ? 6u : 7u;
    return s | c;
}

// Stage one 256-col (16 KB) fp4 sub-tile global->LDS with 256 threads:
// 4 x global_load_lds(16B) per thread.  LDS dest linear; global src XOR-pre-
// swizzled on the 16B-slot index (bits 5:4) with key (row&3)^((row>>2)&3)
// (row = off>>6 at 64 B/row) — involution; makes the 16-lane fragment reads
// exactly 2-way bank-aliased (free, m136).
__device__ __forceinline__ void stage_sub4(const char* __restrict__ gsrc,
                                           char* lds, int w, int lane) {
    #pragma unroll
    for (int it = 0; it < 4; ++it) {
        int off = w * 4096 + it * 1024 + lane * 16;
        int key = ((off >> 6) & 3) ^ ((off >> 8) & 3);
        int swz = off ^ (key << 4);
        __builtin_amdgcn_global_load_lds((gas_u32)(gsrc + swz),
                                         (las_u32)(lds + w * 4096 + it * 1024),
                                         16, 0, 0);
    }
}

// ---------------------------------------------------------------------------
// Kernel 1: L2-normalize rows; store fp4(e2m1) Z = [z1n; z2n] pre-folded by
// 8*SCALE_S (with 2^-3 e8m0 scales on both MFMA operands the product is
// exactly SCALE_S^2 * z.z = the exp2 argument); fp32 cross dot; zero R and
// the output scalar.
// ---------------------------------------------------------------------------
__global__ __launch_bounds__(256) void norm_kernel(
    const float* __restrict__ outp, const float* __restrict__ augp,
    unsigned char* __restrict__ Zf4, float* __restrict__ R,
    float* __restrict__ posdot, float* __restrict__ outf)
{
    int gt = blockIdx.x * 256 + threadIdx.x;
    if (gt < M) R[gt] = 0.0f;
    if (gt == 0) outf[0] = 0.0f;

    const int w    = threadIdx.x >> 6;
    const int lane = threadIdx.x & 63;
    const int row  = blockIdx.x * 4 + w;

    float2 a = *(const float2*)(outp + row * 128 + lane * 2);
    float2 b = *(const float2*)(augp + row * 128 + lane * 2);

    float ssa = a.x * a.x + a.y * a.y;
    float ssb = b.x * b.x + b.y * b.y;
    #pragma unroll
    for (int m = 1; m < 64; m <<= 1) {
        ssa += __shfl_xor(ssa, m);
        ssb += __shfl_xor(ssb, m);
    }
    float inva = 1.0f / fmaxf(sqrtf(ssa), 1e-12f);
    float invb = 1.0f / fmaxf(sqrtf(ssb), 1e-12f);

    float xa0 = a.x * inva, xa1 = a.y * inva;   // unit-normalized (fp32)
    float xb0 = b.x * invb, xb1 = b.y * invb;

    unsigned ba = f4enc(xa0 * FOLD) | (f4enc(xa1 * FOLD) << 4);
    unsigned bb = f4enc(xb0 * FOLD) | (f4enc(xb1 * FOLD) << 4);
    Zf4[(size_t)row * 64 + lane]        = (unsigned char)ba;
    Zf4[(size_t)(NR + row) * 64 + lane] = (unsigned char)bb;

    float d = xa0 * xb0 + xa1 * xb1;   // positive-pair dot stays fp32-exact
    #pragma unroll
    for (int m = 1; m < 64; m <<= 1) d += __shfl_xor(d, m);
    if (lane == 0) posdot[row] = d;
}

// ---------------------------------------------------------------------------
// Kernel 2: row sums of exp2(Zs Zs^T) via MX-fp4 K=128 MFMA (fmt 4, 2x fp8
// rate, half the LDS bytes).  R22 structure + two micro-fixes:
//  (1) subtile 128 -> 256 cols (16 KB, dbuf 32 KB): 3 barriers/block
//      instead of 5, doubled inter-barrier runs for wave de-phasing.
//  (2) dual accumulators rsA/rsB alternating by ct parity — halves the
//      dependent f32x4-add chain depth so independent VALU work co-issues
//      under MFMA/trans latency.
// Grid (32 col-chunks, 64 row-blocks) = 2048 blocks; launch_bounds(256,3)
// (R11/R13/R17 lesson: verify VGPR_Count ~70-80, FETCH ~8 MB first).
// Wave owns 64 rows (afrag[4]: K=128 = 16 B/lane, zero-padded i32x8).
// Per ct: ONE swizzled 16B LDS read -> b8 -> 4 MFMA (rt) -> 16 exp2 ->
// 16 adds.  id%8 = ch%8 pins 4 chunks/XCD (Z fp4 = 1 MB, L2-resident).
// ---------------------------------------------------------------------------
__global__ __launch_bounds__(256, 3) void gram_kernel(
    const unsigned char* __restrict__ Zf4, float* __restrict__ R)
{
    __shared__ char buf[2][SUBB];   // 32 KB

    const int tid  = threadIdx.x;
    const int w    = tid >> 6;       // 0..3
    const int lane = tid & 63;
    const int l16  = lane & 15;
    const int lg   = lane >> 4;      // 0..3 (16B k-chunk = 32 fp4 elems)
    const int ch   = blockIdx.x;     // 0..31 (512 cols each)
    const int rb   = blockIdx.y;     // 0..63 (256 rows each)

    const char* Zb = (const char*)Zf4;
    const char* Xg = Zb + (size_t)rb * 16384;     // 256 rows * 64 B
    const char* Yg = Zb + (size_t)ch * 32768;     // 512 cols * 64 B

    // A fragments: 64 rows per wave, full K=128 (16 B/lane), one-time read;
    // upper half of the f8f6f4 operand is unused for fp4 -> zero.
    i32x8 afrag[4];
    #pragma unroll
    for (int rt = 0; rt < 4; ++rt) {
        i32x4 lo = *(const i32x4*)(Xg + (w * 64 + rt * 16 + l16) * 64 + lg * 16);
        afrag[rt] = (i32x8){lo[0], lo[1], lo[2], lo[3], 0, 0, 0, 0};
    }

    stage_sub4(Yg, buf[0], w, lane);
    __syncthreads();

    f32x4 rsA[4], rsB[4];
    #pragma unroll
    for (int rt = 0; rt < 4; ++rt) {
        rsA[rt] = (f32x4){0.f, 0.f, 0.f, 0.f};
        rsB[rt] = (f32x4){0.f, 0.f, 0.f, 0.f};
    }
    const f32x4 zero4 = (f32x4){0.f, 0.f, 0.f, 0.f};

    // lane-constant swizzled LDS read offset; ct adds bits >= 10 only and
    // the swizzle key (r&3)^((r>>2)&3) is invariant under r += 16.
    const int slot  = lg ^ (l16 & 3) ^ ((l16 >> 2) & 3);
    const int addrA = l16 * 64 + (slot << 4);

    #pragma unroll 1
    for (int s = 0; s < 2; ++s) {
        if (s == 0)
            stage_sub4(Yg + SUBB, buf[1], w, lane);

        const char* cur = buf[s];

        #pragma unroll 1
        for (int cb = 0; cb < 4; ++cb) {
            #pragma unroll
            for (int ct = 0; ct < 4; ++ct) {
                const char* p = cur + (cb * 4 + ct) * 1024;
                i32x4 lo = *(const i32x4*)(p + addrA);
                i32x8 b8 = (i32x8){lo[0], lo[1], lo[2], lo[3], 0, 0, 0, 0};
                #pragma unroll
                for (int rt = 0; rt < 4; ++rt) {
                    f32x4 d = __builtin_amdgcn_mfma_scale_f32_16x16x128_f8f6f4(
                        afrag[rt], b8, zero4,
                        4 /*fmtA=fp4*/, 4 /*fmtB=fp4*/,
                        0, SCALE_Q, 0, SCALE_Q);
                    f32x4 e;
                    e[0] = fexp2(d[0]); e[1] = fexp2(d[1]);
                    e[2] = fexp2(d[2]); e[3] = fexp2(d[3]);
                    if (ct & 1) rsB[rt] += e; else rsA[rt] += e;
                }
            }
        }
        __syncthreads();   // stage(s+1) landed + all waves done with cur
    }

    // merge dual accumulators, then reduce across the 16 lanes per row
    #pragma unroll
    for (int rt = 0; rt < 4; ++rt) {
        f32x4 rs = rsA[rt] + rsB[rt];
        #pragma unroll
        for (int q = 0; q < 4; ++q) {
            float v = rs[q];
            v += __shfl_xor(v, 1);  v += __shfl_xor(v, 2);
            v += __shfl_xor(v, 4);  v += __shfl_xor(v, 8);
            if (l16 == 0)
                atomicAdd(&R[rb * 256 + w * 64 + rt * 16 + lg * 4 + q], v);
        }
    }
}

// ---------------------------------------------------------------------------
// Kernel 3: loss = mean_i [ -dot_i/tau + 0.5(log(R_i - E) + log(R_{NR+i} - E)) ]
// 32 blocks x 256 thr, wave-shuffle reduce + one atomicAdd per wave.
// ---------------------------------------------------------------------------
__global__ __launch_bounds__(256) void final_kernel(
    const float* __restrict__ R, const float* __restrict__ posdot,
    float* __restrict__ outv)
{
    const int i = blockIdx.x * 256 + threadIdx.x;   // 0..8191
    float d1 = R[i]      - E_REFL;
    float d2 = R[NR + i] - E_REFL;
    float local = -posdot[i] * INV_T + 0.5f * (logf(d1) + logf(d2));

    #pragma unroll
    for (int m = 1; m < 64; m <<= 1) local += __shfl_xor(local, m);
    if ((threadIdx.x & 63) == 0)
        atomicAdd(outv, local * (1.0f / NR));
}

// ---------------------------------------------------------------------------
extern "C" void kernel_launch(void* const* d_in, const int* in_sizes, int n_in,
                              void* d_out, int out_size, void* d_ws, size_t ws_size,
                              hipStream_t stream) {
    const float* outp = (const float*)d_in[0];
    const float* augp = (const float*)d_in[1];

    char* ws = (char*)d_ws;
    unsigned char* Zf4 = (unsigned char*)ws;                  // 1 MB fp4 [16384][64B]
    float* R      = (float*)(ws + 1048576);                   // 16384 f32 row sums
    float* posdot = (float*)(ws + 1048576 + 65536);           // 8192 f32
    float* outf   = (float*)d_out;

    hipLaunchKernelGGL(norm_kernel, dim3(2048), dim3(256), 0, stream,
                       outp, augp, Zf4, R, posdot, outf);

    hipLaunchKernelGGL(gram_kernel, dim3(32, 64), dim3(256), 0, stream,
                       Zf4, R);

    hipLaunchKernelGGL(final_kernel, dim3(32), dim3(256), 0, stream,
                       R, posdot, outf);
}

// Round 24
// 44.455 us; speedup vs baseline: 1.0485x; 1.0485x over previous
//
#include <hip/hip_runtime.h>
#include <hip/hip_bf16.h>

#define NR  8192      // rows per view
#define M   16384     // 2*NR concatenated
#define SUBB 8192     // 128 cols * 64 B (one fp4 Y sub-tile)

constexpr float INV_T   = 2.5f;                  // 1/0.4
constexpr float SCALE_S = 1.89914134f;           // sqrt(2.5*log2(e)); s^2=2.5*log2e
constexpr float E_REFL  = 12.182493960703473f;   // exp(2.5)
constexpr unsigned SCALE_Q = 0x7C7C7C7Cu;        // e8m0 = 2^-3 in all bytes
constexpr float FOLD = 8.0f * SCALE_S;           // x8 fold, 2^-3 scale each side

typedef int   i32x4 __attribute__((ext_vector_type(4)));
typedef int   i32x8 __attribute__((ext_vector_type(8)));
typedef float f32x4 __attribute__((ext_vector_type(4)));

typedef const __attribute__((address_space(1))) unsigned int* gas_u32;
typedef __attribute__((address_space(3))) unsigned int*       las_u32;

__device__ __forceinline__ float fexp2(float x) {
#if __has_builtin(__builtin_amdgcn_exp2f)
    return __builtin_amdgcn_exp2f(x);
#else
    return exp2f(x);
#endif
}

// fp4 e2m1 encode (round-to-nearest): values {0,.5,1,1.5,2,3,4,6}, bit3=sign
__device__ __forceinline__ unsigned f4enc(float v) {
    unsigned s = v < 0.0f ? 8u : 0u;
    float m = fabsf(v);
    unsigned c = (m < 0.25f) ? 0u : (m < 0.75f) ? 1u : (m < 1.25f) ? 2u :
                 (m < 1.75f) ? 3u : (m < 2.5f)  ? 4u : (m < 3.5f)  ? 5u :
                 (m < 5.0f)  ? 6u : 7u;
    return s | c;
}

// Stage one 128-col (8 KB) fp4 sub-tile global->LDS with 256 threads:
// 2 x global_load_lds(16B) per thread.  LDS dest linear; global src XOR-pre-
// swizzled on the 16B-slot index (bits 5:4) with key (row&3)^((row>>2)&3)
// (row = off>>6 at 64 B/row) — involution; makes the 16-lane fragment reads
// exactly 2-way bank-aliased (free, m136).
__device__ __forceinline__ void stage_sub4(const char* __restrict__ gsrc,
                                           char* lds, int w, int lane) {
    #pragma unroll
    for (int it = 0; it < 2; ++it) {
        int off = w * 2048 + it * 1024 + lane * 16;
        int key = ((off >> 6) & 3) ^ ((off >> 8) & 3);
        int swz = off ^ (key << 4);
        __builtin_amdgcn_global_load_lds((gas_u32)(gsrc + swz),
                                         (las_u32)(lds + w * 2048 + it * 1024),
                                         16, 0, 0);
    }
}

// ---------------------------------------------------------------------------
// Kernel 1: L2-normalize rows; store fp4(e2m1) Z = [z1n; z2n] pre-folded by
// 8*SCALE_S (with 2^-3 e8m0 scales on both MFMA operands the product is
// exactly SCALE_S^2 * z.z = the exp2 argument); fp32 cross dot; zero R and
// the output scalar.
// ---------------------------------------------------------------------------
__global__ __launch_bounds__(256) void norm_kernel(
    const float* __restrict__ outp, const float* __restrict__ augp,
    unsigned char* __restrict__ Zf4, float* __restrict__ R,
    float* __restrict__ posdot, float* __restrict__ outf)
{
    int gt = blockIdx.x * 256 + threadIdx.x;
    if (gt < M) R[gt] = 0.0f;
    if (gt == 0) outf[0] = 0.0f;

    const int w    = threadIdx.x >> 6;
    const int lane = threadIdx.x & 63;
    const int row  = blockIdx.x * 4 + w;

    float2 a = *(const float2*)(outp + row * 128 + lane * 2);
    float2 b = *(const float2*)(augp + row * 128 + lane * 2);

    float ssa = a.x * a.x + a.y * a.y;
    float ssb = b.x * b.x + b.y * b.y;
    #pragma unroll
    for (int m = 1; m < 64; m <<= 1) {
        ssa += __shfl_xor(ssa, m);
        ssb += __shfl_xor(ssb, m);
    }
    float inva = 1.0f / fmaxf(sqrtf(ssa), 1e-12f);
    float invb = 1.0f / fmaxf(sqrtf(ssb), 1e-12f);

    float xa0 = a.x * inva, xa1 = a.y * inva;   // unit-normalized (fp32)
    float xb0 = b.x * invb, xb1 = b.y * invb;

    // fp4 pack: elements 2*lane (low nibble), 2*lane+1 (high nibble)
    unsigned ba = f4enc(xa0 * FOLD) | (f4enc(xa1 * FOLD) << 4);
    unsigned bb = f4enc(xb0 * FOLD) | (f4enc(xb1 * FOLD) << 4);
    Zf4[(size_t)row * 64 + lane]        = (unsigned char)ba;
    Zf4[(size_t)(NR + row) * 64 + lane] = (unsigned char)bb;

    float d = xa0 * xb0 + xa1 * xb1;   // positive-pair dot stays fp32-exact
    #pragma unroll
    for (int m = 1; m < 64; m <<= 1) d += __shfl_xor(d, m);
    if (lane == 0) posdot[row] = d;
}

// ---------------------------------------------------------------------------
// Kernel 2: row sums of exp2(Zs Zs^T) via MX-fp4 K=128 MFMA (fmt 4 = fp4,
// 2x the fp8 rate; half the LDS bytes).  FINAL STRUCTURE (R22, best
// measured 44.4 us total / ~38.6 us gram):
// grid (32 col-chunks, 64 row-blocks) = 2048 blocks; wave owns 64 rows
// (afrag[4]: full K=128 = 16 B/lane, zero-padded to the i32x8 operand);
// Y chunk = 512 cols = 4 subtiles of 128 cols (8 KB), double-buffered
// (16 KB LDS).  Per ct: ONE swizzled 16B LDS read -> b8 (lower half) ->
// 4 MFMA (rt) -> 16 exp2 -> 16 adds.  launch_bounds(256,3).
// id%8 = ch%8 pins 4 chunks/XCD (Z fp4 = 1 MB, fully L2-resident).
// Binding pipe: exp2/accumulate stream (268M exponentials at the
// quarter-rate trans-pipe floor of 13.6 us).  Falsified alternatives
// (measured): symmetry x3 (R3/R10/R20), rt=8 both register regimes
// (R17/R18), counted-vmcnt (R7), single-shot (R14), self-paced (R15),
// direct-L2 B (R8), barrier-halving + dual accumulators (R23), bf16/fp8
// precisions (R2-R21: fp4 strictly dominates within tolerance).
// ---------------------------------------------------------------------------
__global__ __launch_bounds__(256, 3) void gram_kernel(
    const unsigned char* __restrict__ Zf4, float* __restrict__ R)
{
    __shared__ char buf[2][SUBB];   // 16 KB

    const int tid  = threadIdx.x;
    const int w    = tid >> 6;       // 0..3
    const int lane = tid & 63;
    const int l16  = lane & 15;
    const int lg   = lane >> 4;      // 0..3 (16B k-chunk = 32 fp4 elems)
    const int ch   = blockIdx.x;     // 0..31 (512 cols each)
    const int rb   = blockIdx.y;     // 0..63 (256 rows each)

    const char* Zb = (const char*)Zf4;
    const char* Xg = Zb + (size_t)rb * 16384;     // 256 rows * 64 B
    const char* Yg = Zb + (size_t)ch * 32768;     // 512 cols * 64 B

    // A fragments: 64 rows per wave, full K=128 (16 B/lane), one-time read;
    // upper half of the f8f6f4 operand is unused for fp4 -> zero.
    i32x8 afrag[4];
    #pragma unroll
    for (int rt = 0; rt < 4; ++rt) {
        i32x4 lo = *(const i32x4*)(Xg + (w * 64 + rt * 16 + l16) * 64 + lg * 16);
        afrag[rt] = (i32x8){lo[0], lo[1], lo[2], lo[3], 0, 0, 0, 0};
    }

    stage_sub4(Yg, buf[0], w, lane);
    __syncthreads();

    f32x4 rs[4];
    #pragma unroll
    for (int rt = 0; rt < 4; ++rt) rs[rt] = (f32x4){0.f, 0.f, 0.f, 0.f};
    const f32x4 zero4 = (f32x4){0.f, 0.f, 0.f, 0.f};

    // lane-constant swizzled LDS read offset; ct adds bits >= 10 only and
    // the swizzle key (r&3)^((r>>2)&3) is invariant under r += 16.
    const int slot  = lg ^ (l16 & 3) ^ ((l16 >> 2) & 3);
    const int addrA = l16 * 64 + (slot << 4);

    #pragma unroll 1
    for (int s = 0; s < 4; ++s) {
        if (s + 1 < 4)
            stage_sub4(Yg + (size_t)(s + 1) * SUBB, buf[(s + 1) & 1], w, lane);

        const char* cur = buf[s & 1];

        #pragma unroll 1
        for (int cb = 0; cb < 2; ++cb) {
            #pragma unroll
            for (int ct = 0; ct < 4; ++ct) {
                const char* p = cur + (cb * 4 + ct) * 1024;
                i32x4 lo = *(const i32x4*)(p + addrA);
                i32x8 b8 = (i32x8){lo[0], lo[1], lo[2], lo[3], 0, 0, 0, 0};
                #pragma unroll
                for (int rt = 0; rt < 4; ++rt) {
                    f32x4 d = __builtin_amdgcn_mfma_scale_f32_16x16x128_f8f6f4(
                        afrag[rt], b8, zero4,
                        4 /*fmtA=fp4*/, 4 /*fmtB=fp4*/,
                        0, SCALE_Q, 0, SCALE_Q);
                    f32x4 e;
                    e[0] = fexp2(d[0]); e[1] = fexp2(d[1]);
                    e[2] = fexp2(d[2]); e[3] = fexp2(d[3]);
                    rs[rt] += e;
                }
            }
        }
        __syncthreads();   // stage(s+1) landed + all waves done with cur
    }

    // reduce row sums across the 16 lanes holding one row's columns
    #pragma unroll
    for (int rt = 0; rt < 4; ++rt)
        #pragma unroll
        for (int q = 0; q < 4; ++q) {
            float v = rs[rt][q];
            v += __shfl_xor(v, 1);  v += __shfl_xor(v, 2);
            v += __shfl_xor(v, 4);  v += __shfl_xor(v, 8);
            if (l16 == 0)
                atomicAdd(&R[rb * 256 + w * 64 + rt * 16 + lg * 4 + q], v);
        }
}

// ---------------------------------------------------------------------------
// Kernel 3: loss = mean_i [ -dot_i/tau + 0.5(log(R_i - E) + log(R_{NR+i} - E)) ]
// 32 blocks x 256 thr, wave-shuffle reduce + one atomicAdd per wave.
// ---------------------------------------------------------------------------
__global__ __launch_bounds__(256) void final_kernel(
    const float* __restrict__ R, const float* __restrict__ posdot,
    float* __restrict__ outv)
{
    const int i = blockIdx.x * 256 + threadIdx.x;   // 0..8191
    float d1 = R[i]      - E_REFL;
    float d2 = R[NR + i] - E_REFL;
    float local = -posdot[i] * INV_T + 0.5f * (logf(d1) + logf(d2));

    #pragma unroll
    for (int m = 1; m < 64; m <<= 1) local += __shfl_xor(local, m);
    if ((threadIdx.x & 63) == 0)
        atomicAdd(outv, local * (1.0f / NR));
}

// ---------------------------------------------------------------------------
extern "C" void kernel_launch(void* const* d_in, const int* in_sizes, int n_in,
                              void* d_out, int out_size, void* d_ws, size_t ws_size,
                              hipStream_t stream) {
    const float* outp = (const float*)d_in[0];
    const float* augp = (const float*)d_in[1];

    char* ws = (char*)d_ws;
    unsigned char* Zf4 = (unsigned char*)ws;                  // 1 MB fp4 [16384][64B]
    float* R      = (float*)(ws + 1048576);                   // 16384 f32 row sums
    float* posdot = (float*)(ws + 1048576 + 65536);           // 8192 f32
    float* outf   = (float*)d_out;

    hipLaunchKernelGGL(norm_kernel, dim3(2048), dim3(256), 0, stream,
                       outp, augp, Zf4, R, posdot, outf);

    hipLaunchKernelGGL(gram_kernel, dim3(32, 64), dim3(256), 0, stream,
                       Zf4, R);

    hipLaunchKernelGGL(final_kernel, dim3(32), dim3(256), 0, stream,
                       R, posdot, outf);
}